// Round 1
// baseline (612.208 us; speedup 1.0000x reference)
//
#include <hip/hip_runtime.h>

#define B_ 8
#define C_ 192
#define N_ 13824     // 24^3
#define HEADS 6
#define HD 32
#define THREEC 576

typedef unsigned short ushort_t;
typedef unsigned int uint_t;

__device__ __forceinline__ float bf2f(ushort_t u) {
  union { uint_t u; float f; } c; c.u = ((uint_t)u) << 16; return c.f;
}
__device__ __forceinline__ ushort_t f2bf(float f) {
  union { float f; uint_t u; } c; c.f = f;
  uint_t u = c.u;
  uint_t r = (u + 0x7fffu + ((u >> 16) & 1u)) >> 16;  // RNE (finite values)
  return (ushort_t)r;
}

// ---------------------------------------------------------------------------
// K1: qkv[b][o][n] = sum_c qkv_w[o][c] * x[b][c][n] + qkv_b[o], stored bf16.
// M=576 (o), K=192 (c), N=13824 (n), per batch. BM=96, BN=256, BK=16.
// grid (54, 6, 8), block 256, thread tile 12(o) x 8(n).
// ---------------------------------------------------------------------------
__global__ __launch_bounds__(256) void qkv_gemm(
    const float* __restrict__ x, const float* __restrict__ w,
    const float* __restrict__ bias, ushort_t* __restrict__ qkv) {
  __shared__ float As[16][100];   // [k][o], pad 100 (mult of 4 for b128 align)
  __shared__ float Bs[16][256];   // [k][n]
  int t = threadIdx.x;
  int bx = blockIdx.x, by = blockIdx.y, b = blockIdx.z;
  int n0 = bx * 256, o0 = by * 96;
  int tn = t & 31, tm = t >> 5;   // tn: n-group (8 each), tm: o-group (12 each)
  const float* xb = x + (size_t)b * C_ * N_;

  float acc[12][8];
#pragma unroll
  for (int i = 0; i < 12; ++i)
#pragma unroll
    for (int j = 0; j < 8; ++j) acc[i][j] = 0.f;

  for (int kt = 0; kt < 12; ++kt) {
    int c0 = kt * 16;
    // A tile 96x16 -> As[k][o] (transposed store). 384 float4 loads.
#pragma unroll
    for (int i = 0; i < 2; ++i) {
      int idx = t + i * 256;
      if (idx < 384) {
        int o_l = idx >> 2, c4 = idx & 3;
        float4 a4 = *(const float4*)&w[(size_t)(o0 + o_l) * C_ + c0 + c4 * 4];
        As[c4 * 4 + 0][o_l] = a4.x;
        As[c4 * 4 + 1][o_l] = a4.y;
        As[c4 * 4 + 2][o_l] = a4.z;
        As[c4 * 4 + 3][o_l] = a4.w;
      }
    }
    // B tile 16x256, coalesced float4.
#pragma unroll
    for (int i = 0; i < 4; ++i) {
      int idx = t + i * 256;
      int k_l = idx >> 6, nl4 = idx & 63;
      float4 b4 = *(const float4*)&xb[(size_t)(c0 + k_l) * N_ + n0 + nl4 * 4];
      *(float4*)&Bs[k_l][nl4 * 4] = b4;
    }
    __syncthreads();
#pragma unroll
    for (int k = 0; k < 16; ++k) {
      float a[12], bb[8];
      *(float4*)&a[0] = *(const float4*)&As[k][tm * 12];
      *(float4*)&a[4] = *(const float4*)&As[k][tm * 12 + 4];
      *(float4*)&a[8] = *(const float4*)&As[k][tm * 12 + 8];
      *(float4*)&bb[0] = *(const float4*)&Bs[k][tn * 8];
      *(float4*)&bb[4] = *(const float4*)&Bs[k][tn * 8 + 4];
#pragma unroll
      for (int i = 0; i < 12; ++i)
#pragma unroll
        for (int j = 0; j < 8; ++j)
          acc[i][j] = fmaf(a[i], bb[j], acc[i][j]);
    }
    __syncthreads();
  }
  // epilogue: +bias, convert bf16, 16B stores
#pragma unroll
  for (int i = 0; i < 12; ++i) {
    int o = o0 + tm * 12 + i;
    float bv = bias[o];
    union { ushort_t us[8]; uint4 v; } pk;
#pragma unroll
    for (int j = 0; j < 8; ++j) pk.us[j] = f2bf(acc[i][j] + bv);
    *(uint4*)(qkv + (size_t)(b * THREEC + o) * N_ + n0 + tn * 8) = pk.v;
  }
}

// ---------------------------------------------------------------------------
// K2: per (b,h,chunk): partial S[c][d]=sum_n2 q_c*k_d, nq[c]=sum q^2, nk[d]=sum k^2
// over n2 in [chunk*1728, +1728). q[b,h,d,n2] = qkv[b][n2/24][(n2%24)*576 + h*32 + d]
// (k at +192). grid (8, 6, 8) = (chunk, h, b), block 256.
// Spart layout per (b,h,chunk): [0..1024) S, [1024..1056) nq, [1056..1088) nk.
// ---------------------------------------------------------------------------
__global__ __launch_bounds__(256) void attn_partial(
    const ushort_t* __restrict__ qkv, float* __restrict__ Spart) {
  __shared__ float sh[4608];  // qs[64][32] | ks[64][32] | redq[8][32] | redk[8][32]
  int t = threadIdx.x;
  int chunk = blockIdx.x, h = blockIdx.y, b = blockIdx.z;
  int j = t & 31, g8 = t >> 5;          // load mapping
  int tg = t >> 6, tl = t & 63;         // compute mapping (tg = wave id)
  int c0 = (tl & 7) * 4, d0 = (tl >> 3) * 4;
  float acc[4][4];
#pragma unroll
  for (int i = 0; i < 4; ++i)
#pragma unroll
    for (int m = 0; m < 4; ++m) acc[i][m] = 0.f;
  float sqq = 0.f, sqk = 0.f;
  const ushort_t* basep = qkv + (size_t)b * THREEC * N_;
  int n2base = chunk * 1728;

  for (int p = 0; p < 27; ++p) {
    __syncthreads();
#pragma unroll
    for (int i = 0; i < 8; ++i) {
      int n2l = g8 * 8 + i;
      int n2 = n2base + p * 64 + n2l;
      int o = n2 / 24, r = n2 - o * 24;
      const ushort_t* rp = basep + (size_t)o * N_ + r * THREEC + h * HD + j;
      float qv = bf2f(rp[0]);
      float kv = bf2f(rp[C_]);
      sh[n2l * 32 + j] = qv;
      sh[2048 + n2l * 32 + j] = kv;
      sqq = fmaf(qv, qv, sqq);
      sqk = fmaf(kv, kv, sqk);
    }
    __syncthreads();
#pragma unroll
    for (int i = 0; i < 16; ++i) {
      int n2l = tg * 16 + i;
      float4 q4 = *(const float4*)&sh[n2l * 32 + c0];
      float4 k4 = *(const float4*)&sh[2048 + n2l * 32 + d0];
      float q[4] = {q4.x, q4.y, q4.z, q4.w};
      float kk[4] = {k4.x, k4.y, k4.z, k4.w};
#pragma unroll
      for (int ii = 0; ii < 4; ++ii)
#pragma unroll
        for (int mm = 0; mm < 4; ++mm)
          acc[ii][mm] = fmaf(q[ii], kk[mm], acc[ii][mm]);
    }
  }
  __syncthreads();  // all LDS reads done; reuse sh[0..4096) as reduction scratch
#pragma unroll
  for (int ii = 0; ii < 4; ++ii)
#pragma unroll
    for (int mm = 0; mm < 4; ++mm)
      sh[tg * 1024 + (c0 + ii) * 32 + (d0 + mm)] = acc[ii][mm];
  sh[4096 + g8 * 32 + j] = sqq;
  sh[4352 + g8 * 32 + j] = sqk;
  __syncthreads();

  float* outp = Spart + (size_t)((b * HEADS + h) * 8 + chunk) * 1088;
  for (int e = t; e < 1024; e += 256)
    outp[e] = sh[e] + sh[1024 + e] + sh[2048 + e] + sh[3072 + e];
  if (t < 32) {
    float s = 0.f;
#pragma unroll
    for (int g = 0; g < 8; ++g) s += sh[4096 + g * 32 + t];
    outp[1024 + t] = s;
  } else if (t < 64) {
    int jj = t - 32;
    float s = 0.f;
#pragma unroll
    for (int g = 0; g < 8; ++g) s += sh[4352 + g * 32 + jj];
    outp[1056 + jj] = s;
  }
}

// ---------------------------------------------------------------------------
// K3: reduce partials, logits = temp[h]*S[c][d]/(max(|q_c|,eps)*max(|k_d|,eps)),
// softmax over d, then W2t[b][k=h*32+d][co] = sum_c proj_w[co][c*6+h]*attn[c][d].
// grid (6, 8) = (h, b), block 256.
// ---------------------------------------------------------------------------
__global__ __launch_bounds__(256) void attn_final(
    const float* __restrict__ Spart, const float* __restrict__ temp,
    const float* __restrict__ proj_w, float* __restrict__ W2t) {
  __shared__ float Sl[1024];
  __shared__ float invq[32], invk[32];
  __shared__ float Pl[192 * 33];  // proj_w[:, c*6+h] slice, padded
  int t = threadIdx.x;
  int h = blockIdx.x, b = blockIdx.y;
  const float* base = Spart + (size_t)((b * HEADS + h) * 8) * 1088;

  for (int e = t; e < 1024; e += 256) {
    float s = 0.f;
#pragma unroll
    for (int ch = 0; ch < 8; ++ch) s += base[ch * 1088 + e];
    Sl[e] = s;
  }
  if (t < 64) {
    int jj = t & 31;
    int off = 1024 + (t >> 5) * 32 + jj;
    float s = 0.f;
#pragma unroll
    for (int ch = 0; ch < 8; ++ch) s += base[ch * 1088 + off];
    float inv = 1.f / fmaxf(sqrtf(s), 1e-12f);
    if (t < 32) invq[jj] = inv; else invk[jj] = inv;
  }
  // stage proj_w column slice: Pl[co][c] = proj_w[co*192 + c*6 + h]
  for (int e = t; e < 6144; e += 256) {
    int co = e >> 5, c = e & 31;
    Pl[co * 33 + c] = proj_w[(size_t)co * C_ + c * HEADS + h];
  }
  __syncthreads();

  // softmax: row c = t>>3, 8 lanes per row, 4 d's each
  {
    int c = t >> 3, l8 = t & 7;
    float tmpv = temp[h];
    float iq = invq[c];
    float lg[4];
#pragma unroll
    for (int m = 0; m < 4; ++m) {
      int d = l8 * 4 + m;
      lg[m] = Sl[c * 32 + d] * iq * invk[d] * tmpv;
    }
    float mx = fmaxf(fmaxf(lg[0], lg[1]), fmaxf(lg[2], lg[3]));
    for (int off = 1; off < 8; off <<= 1) mx = fmaxf(mx, __shfl_xor(mx, off, 8));
    float ex[4]; float ssum = 0.f;
#pragma unroll
    for (int m = 0; m < 4; ++m) { ex[m] = __expf(lg[m] - mx); ssum += ex[m]; }
    for (int off = 1; off < 8; off <<= 1) ssum += __shfl_xor(ssum, off, 8);
    float inv = 1.f / ssum;
#pragma unroll
    for (int m = 0; m < 4; ++m) Sl[c * 32 + l8 * 4 + m] = ex[m] * inv;  // attn in place
  }
  __syncthreads();

  // W2t: 32 (kd) x 192 (co); lanes sweep co (coalesced writes)
  for (int e2 = t; e2 < 6144; e2 += 256) {
    int kd = e2 / 192;
    int co = e2 - kd * 192;
    float s = 0.f;
#pragma unroll
    for (int c = 0; c < 32; ++c)
      s = fmaf(Pl[co * 33 + c], Sl[c * 32 + kd], s);
    W2t[((size_t)b * C_ + h * HD + kd) * C_ + co] = s;
  }
}

// ---------------------------------------------------------------------------
// K4: y[b][co][n2] = proj_b[co] + sum_j W2t[b][j][co] * V[b][j][n2],
// V[b][j][n2] = qkv[b][n2/24][(n2%24)*576 + 384 + j]  (contiguous in j).
// grid (216, 8), block 256. 64 n2-columns staged in LDS; each wave owns 48 co's
// (wave-uniform -> W2t rows become scalar loads).
// ---------------------------------------------------------------------------
__global__ __launch_bounds__(256) void proj_gemm(
    const ushort_t* __restrict__ qkv, const float* __restrict__ W2t,
    const float* __restrict__ pb, float* __restrict__ y) {
  __shared__ float Vs[192 * 65];  // [j][n2l], pad 65: <=2-way banks both ways
  int t = threadIdx.x;
  int nb = blockIdx.x, b = blockIdx.y;
  int n2_0 = nb * 64;
  const ushort_t* basep = qkv + (size_t)b * THREEC * N_;
#pragma unroll 4
  for (int i = 0; i < 48; ++i) {
    int idx = t + i * 256;
    int n2l = idx / 192;
    int jj = idx - n2l * 192;
    int n2 = n2_0 + n2l;
    int o = n2 / 24, r = n2 - o * 24;
    Vs[jj * 65 + n2l] = bf2f(basep[(size_t)o * N_ + r * THREEC + 384 + jj]);
  }
  __syncthreads();

  int n2l = t & 63;
  int cg = __builtin_amdgcn_readfirstlane(t >> 6);  // wave id, provably uniform
  int co0 = cg * 48;
  const float* w2b = W2t + (size_t)b * C_ * C_ + co0;
  float acc[48];
#pragma unroll
  for (int i = 0; i < 48; ++i) acc[i] = 0.f;

  for (int k = 0; k < 192; ++k) {
    float v = Vs[k * 65 + n2l];
    const float* wk = w2b + (size_t)k * C_;
#pragma unroll
    for (int i = 0; i < 48; ++i) acc[i] = fmaf(wk[i], v, acc[i]);
  }

  float* yb = y + ((size_t)b * C_ + co0) * N_ + n2_0 + n2l;
#pragma unroll
  for (int i = 0; i < 48; ++i)
    yb[(size_t)i * N_] = acc[i] + pb[co0 + i];
}

// ---------------------------------------------------------------------------
extern "C" void kernel_launch(void* const* d_in, const int* in_sizes, int n_in,
                              void* d_out, int out_size, void* d_ws, size_t ws_size,
                              hipStream_t stream) {
  const float* x      = (const float*)d_in[0];
  const float* qkv_w  = (const float*)d_in[1];
  const float* qkv_b  = (const float*)d_in[2];
  const float* temp   = (const float*)d_in[3];
  const float* proj_w = (const float*)d_in[4];
  const float* proj_b = (const float*)d_in[5];
  float* y = (float*)d_out;

  // ws: [qkv bf16: 8*576*13824 = 127.4 MB][Spart: 417792 f][W2t: 294912 f]
  ushort_t* qkv = (ushort_t*)d_ws;
  size_t qkv_elems = (size_t)B_ * THREEC * N_;
  float* Spart = (float*)((char*)d_ws + qkv_elems * sizeof(ushort_t));
  float* W2t = Spart + (size_t)B_ * HEADS * 8 * 1088;

  qkv_gemm<<<dim3(54, 6, B_), 256, 0, stream>>>(x, qkv_w, qkv_b, qkv);
  attn_partial<<<dim3(8, HEADS, B_), 256, 0, stream>>>(qkv, Spart);
  attn_final<<<dim3(HEADS, B_), 256, 0, stream>>>(Spart, temp, proj_w, W2t);
  proj_gemm<<<dim3(216, B_), 256, 0, stream>>>(qkv, W2t, proj_b, y);
}

// Round 2
// 456.218 us; speedup vs baseline: 1.3419x; 1.3419x over previous
//
#include <hip/hip_runtime.h>

#define B_ 8
#define C_ 192
#define N_ 13824     // 24^3
#define HEADS 6
#define HD 32
#define THREEC 576

typedef unsigned short ushort_t;
typedef unsigned int uint_t;
typedef __attribute__((ext_vector_type(8))) short short8;
typedef __attribute__((ext_vector_type(4))) float f32x4;

__device__ __forceinline__ float bf2f(ushort_t u) {
  union { uint_t u; float f; } c; c.u = ((uint_t)u) << 16; return c.f;
}
__device__ __forceinline__ ushort_t f2bf(float f) {
  union { float f; uint_t u; } c; c.f = f;
  uint_t u = c.u;
  uint_t r = (u + 0x7fffu + ((u >> 16) & 1u)) >> 16;  // RNE (finite values)
  return (ushort_t)r;
}
__device__ __forceinline__ void ldsload16(const void* g, void* l) {
  __builtin_amdgcn_global_load_lds(
      (const __attribute__((address_space(1))) unsigned int*)g,
      (__attribute__((address_space(3))) unsigned int*)l, 16, 0, 0);
}

// ---------------------------------------------------------------------------
// K0a: qkv_w fp32 -> bf16 (row-major [o][c], k-contiguous already). grid 54.
// ---------------------------------------------------------------------------
__global__ __launch_bounds__(256) void wconv(const float* __restrict__ w,
                                             ushort_t* __restrict__ wbf) {
  int idx = (blockIdx.x * 256 + threadIdx.x) * 8;  // 54*256*8 = 110592
  float4 v0 = *(const float4*)&w[idx];
  float4 v1 = *(const float4*)&w[idx + 4];
  union { ushort_t us[8]; uint4 v; } pk;
  pk.us[0] = f2bf(v0.x); pk.us[1] = f2bf(v0.y); pk.us[2] = f2bf(v0.z); pk.us[3] = f2bf(v0.w);
  pk.us[4] = f2bf(v1.x); pk.us[5] = f2bf(v1.y); pk.us[6] = f2bf(v1.z); pk.us[7] = f2bf(v1.w);
  *(uint4*)&wbf[idx] = pk.v;
}

// ---------------------------------------------------------------------------
// K0b: transpose+convert x[b][c][n] fp32 -> xT[b][n][c] bf16. grid (216, 8).
// Memory-bound (212 MB); LDS conflicts hidden under HBM latency.
// ---------------------------------------------------------------------------
__global__ __launch_bounds__(256) void xt_conv(const float* __restrict__ x,
                                               ushort_t* __restrict__ xT) {
  __shared__ ushort_t tile[64 * 200];  // stride 200 shorts = 400B, 16B-aligned rows
  int t = threadIdx.x;
  int n0 = blockIdx.x * 64, b = blockIdx.y;
  const float* xb = x + (size_t)b * C_ * N_;
  int n4 = t & 15, cp = t >> 4;
#pragma unroll
  for (int it = 0; it < 6; ++it) {
    int c = (cp + it * 16) * 2;
    float4 v0 = *(const float4*)&xb[(size_t)c * N_ + n0 + n4 * 4];
    float4 v1 = *(const float4*)&xb[(size_t)(c + 1) * N_ + n0 + n4 * 4];
    float a0[4] = {v0.x, v0.y, v0.z, v0.w};
    float a1[4] = {v1.x, v1.y, v1.z, v1.w};
#pragma unroll
    for (int i = 0; i < 4; ++i) {
      uint_t wd = (uint_t)f2bf(a0[i]) | ((uint_t)f2bf(a1[i]) << 16);
      *(uint_t*)&tile[(n4 * 4 + i) * 200 + c] = wd;
    }
  }
  __syncthreads();
  ushort_t* xTb = xT + ((size_t)b * N_ + n0) * C_;
  int r = t >> 2, q = t & 3;
#pragma unroll
  for (int j = 0; j < 6; ++j) {
    int chunk = q * 6 + j;  // 24 x uint4 per 192-short row
    uint4 v = *(const uint4*)&tile[r * 200 + chunk * 8];
    *(uint4*)&xTb[r * 192 + chunk * 8] = v;
  }
}

// ---------------------------------------------------------------------------
// K1: MFMA bf16 GEMM: qkv[b][o][n] = sum_c wbf[o][c]*xT[b][n][c] + bias[o].
// BM=64 (o), BN=128 (n), K=192 one-shot in LDS (72 KB, 2 blocks/CU).
// grid (9, 108, 8) — o-tile fastest so 9 blocks share an xT tile in L2.
// 4 waves: 2x2 wave grid, each wave 32(o) x 64(n) = 2x4 frags of 16x16x32.
// ---------------------------------------------------------------------------
__global__ __launch_bounds__(256) void qkv_gemm_mfma(
    const ushort_t* __restrict__ wbf, const ushort_t* __restrict__ xT,
    const float* __restrict__ bias, ushort_t* __restrict__ qkv) {
  __shared__ ushort_t As[64 * 192];   // [o][c] rows 384B (16B-aligned)
  __shared__ ushort_t Bs[128 * 192];  // [n][c]
  int t = threadIdx.x;
  int o0 = blockIdx.x * 64, n0 = blockIdx.y * 128, b = blockIdx.z;
  int w = t >> 6, lane = t & 63;
  int ln16 = lane & 15, q4 = lane >> 4;

  // ---- stage A (24 KB) + B (48 KB) via global_load_lds width=16 ----
  const char* Asrc = (const char*)(wbf + (size_t)o0 * C_);
  const char* Bsrc = (const char*)(xT + ((size_t)b * N_ + n0) * C_);
  char* Asl = (char*)As;
  char* Bsl = (char*)Bs;
#pragma unroll
  for (int j = 0; j < 6; ++j) {
    int off = (w * 6 + j) * 1024;
    ldsload16(Asrc + off + lane * 16, Asl + off);
  }
#pragma unroll
  for (int j = 0; j < 12; ++j) {
    int off = (w * 12 + j) * 1024;
    ldsload16(Bsrc + off + lane * 16, Bsl + off);
  }

  // per-wave bias registers: o_local = (w>>1)*32 + mi*16 + q4*4 + r
  float breg[2][4];
#pragma unroll
  for (int mi = 0; mi < 2; ++mi)
#pragma unroll
    for (int r = 0; r < 4; ++r)
      breg[mi][r] = bias[o0 + (w >> 1) * 32 + mi * 16 + q4 * 4 + r];

  f32x4 acc[2][4];
#pragma unroll
  for (int mi = 0; mi < 2; ++mi)
#pragma unroll
    for (int ni = 0; ni < 4; ++ni) acc[mi][ni] = (f32x4){0.f, 0.f, 0.f, 0.f};

  __syncthreads();  // drains vmcnt for global_load_lds

  int mrow = (w >> 1) * 32, ncol = (w & 1) * 64;
#pragma unroll
  for (int kk = 0; kk < 6; ++kk) {
    int k0 = kk * 32 + q4 * 8;
    short8 a[2], bb[4];
#pragma unroll
    for (int mi = 0; mi < 2; ++mi)
      a[mi] = *(const short8*)&As[(mrow + mi * 16 + ln16) * 192 + k0];
#pragma unroll
    for (int ni = 0; ni < 4; ++ni)
      bb[ni] = *(const short8*)&Bs[(ncol + ni * 16 + ln16) * 192 + k0];
#pragma unroll
    for (int mi = 0; mi < 2; ++mi)
#pragma unroll
      for (int ni = 0; ni < 4; ++ni)
        acc[mi][ni] = __builtin_amdgcn_mfma_f32_16x16x32_bf16(
            a[mi], bb[ni], acc[mi][ni], 0, 0, 0);
  }

  // ---- epilogue: +bias, bf16, pack n-pairs via shfl, b32 stores ----
#pragma unroll
  for (int mi = 0; mi < 2; ++mi)
#pragma unroll
    for (int ni = 0; ni < 4; ++ni)
#pragma unroll
      for (int r = 0; r < 4; ++r) {
        float v = acc[mi][ni][r] + breg[mi][r];
        uint_t bf = f2bf(v);
        uint_t pv = (uint_t)__shfl_xor((int)bf, 1);
        if (!(lane & 1)) {
          int o_l = mrow + mi * 16 + q4 * 4 + r;
          int n_l = ncol + ni * 16 + ln16;
          *(uint_t*)&qkv[(size_t)(b * THREEC + o0 + o_l) * N_ + n0 + n_l] =
              bf | (pv << 16);
        }
      }
}

// ---------------------------------------------------------------------------
// K2: per (b,h,chunk): partial S[c][d]=sum_n2 q_c*k_d, nq[c]=sum q^2, nk[d]=sum k^2
// over n2 in [chunk*1728, +1728). q[b,h,d,n2] = qkv[b][n2/24][(n2%24)*576 + h*32 + d]
// (k at +192). grid (8, 6, 8) = (chunk, h, b), block 256.
// ---------------------------------------------------------------------------
__global__ __launch_bounds__(256) void attn_partial(
    const ushort_t* __restrict__ qkv, float* __restrict__ Spart) {
  __shared__ float sh[4608];  // qs[64][32] | ks[64][32] | redq[8][32] | redk[8][32]
  int t = threadIdx.x;
  int chunk = blockIdx.x, h = blockIdx.y, b = blockIdx.z;
  int j = t & 31, g8 = t >> 5;
  int tg = t >> 6, tl = t & 63;
  int c0 = (tl & 7) * 4, d0 = (tl >> 3) * 4;
  float acc[4][4];
#pragma unroll
  for (int i = 0; i < 4; ++i)
#pragma unroll
    for (int m = 0; m < 4; ++m) acc[i][m] = 0.f;
  float sqq = 0.f, sqk = 0.f;
  const ushort_t* basep = qkv + (size_t)b * THREEC * N_;
  int n2base = chunk * 1728;

  for (int p = 0; p < 27; ++p) {
    __syncthreads();
#pragma unroll
    for (int i = 0; i < 8; ++i) {
      int n2l = g8 * 8 + i;
      int n2 = n2base + p * 64 + n2l;
      int o = n2 / 24, r = n2 - o * 24;
      const ushort_t* rp = basep + (size_t)o * N_ + r * THREEC + h * HD + j;
      float qv = bf2f(rp[0]);
      float kv = bf2f(rp[C_]);
      sh[n2l * 32 + j] = qv;
      sh[2048 + n2l * 32 + j] = kv;
      sqq = fmaf(qv, qv, sqq);
      sqk = fmaf(kv, kv, sqk);
    }
    __syncthreads();
#pragma unroll
    for (int i = 0; i < 16; ++i) {
      int n2l = tg * 16 + i;
      float4 q4 = *(const float4*)&sh[n2l * 32 + c0];
      float4 k4 = *(const float4*)&sh[2048 + n2l * 32 + d0];
      float q[4] = {q4.x, q4.y, q4.z, q4.w};
      float kk[4] = {k4.x, k4.y, k4.z, k4.w};
#pragma unroll
      for (int ii = 0; ii < 4; ++ii)
#pragma unroll
        for (int mm = 0; mm < 4; ++mm)
          acc[ii][mm] = fmaf(q[ii], kk[mm], acc[ii][mm]);
    }
  }
  __syncthreads();
#pragma unroll
  for (int ii = 0; ii < 4; ++ii)
#pragma unroll
    for (int mm = 0; mm < 4; ++mm)
      sh[tg * 1024 + (c0 + ii) * 32 + (d0 + mm)] = acc[ii][mm];
  sh[4096 + g8 * 32 + j] = sqq;
  sh[4352 + g8 * 32 + j] = sqk;
  __syncthreads();

  float* outp = Spart + (size_t)((b * HEADS + h) * 8 + chunk) * 1088;
  for (int e = t; e < 1024; e += 256)
    outp[e] = sh[e] + sh[1024 + e] + sh[2048 + e] + sh[3072 + e];
  if (t < 32) {
    float s = 0.f;
#pragma unroll
    for (int g = 0; g < 8; ++g) s += sh[4096 + g * 32 + t];
    outp[1024 + t] = s;
  } else if (t < 64) {
    int jj = t - 32;
    float s = 0.f;
#pragma unroll
    for (int g = 0; g < 8; ++g) s += sh[4352 + g * 32 + jj];
    outp[1056 + jj] = s;
  }
}

// ---------------------------------------------------------------------------
// K3: reduce partials, softmax over d, W2t[b][h*32+d][co] = sum_c proj_w[co][c*6+h]*attn[c][d]
// grid (6, 8) = (h, b), block 256.
// ---------------------------------------------------------------------------
__global__ __launch_bounds__(256) void attn_final(
    const float* __restrict__ Spart, const float* __restrict__ temp,
    const float* __restrict__ proj_w, float* __restrict__ W2t) {
  __shared__ float Sl[1024];
  __shared__ float invq[32], invk[32];
  __shared__ float Pl[192 * 33];
  int t = threadIdx.x;
  int h = blockIdx.x, b = blockIdx.y;
  const float* base = Spart + (size_t)((b * HEADS + h) * 8) * 1088;

  for (int e = t; e < 1024; e += 256) {
    float s = 0.f;
#pragma unroll
    for (int ch = 0; ch < 8; ++ch) s += base[ch * 1088 + e];
    Sl[e] = s;
  }
  if (t < 64) {
    int jj = t & 31;
    int off = 1024 + (t >> 5) * 32 + jj;
    float s = 0.f;
#pragma unroll
    for (int ch = 0; ch < 8; ++ch) s += base[ch * 1088 + off];
    float inv = 1.f / fmaxf(sqrtf(s), 1e-12f);
    if (t < 32) invq[jj] = inv; else invk[jj] = inv;
  }
  for (int e = t; e < 6144; e += 256) {
    int co = e >> 5, c = e & 31;
    Pl[co * 33 + c] = proj_w[(size_t)co * C_ + c * HEADS + h];
  }
  __syncthreads();

  {
    int c = t >> 3, l8 = t & 7;
    float tmpv = temp[h];
    float iq = invq[c];
    float lg[4];
#pragma unroll
    for (int m = 0; m < 4; ++m) {
      int d = l8 * 4 + m;
      lg[m] = Sl[c * 32 + d] * iq * invk[d] * tmpv;
    }
    float mx = fmaxf(fmaxf(lg[0], lg[1]), fmaxf(lg[2], lg[3]));
    for (int off = 1; off < 8; off <<= 1) mx = fmaxf(mx, __shfl_xor(mx, off, 8));
    float ex[4]; float ssum = 0.f;
#pragma unroll
    for (int m = 0; m < 4; ++m) { ex[m] = __expf(lg[m] - mx); ssum += ex[m]; }
    for (int off = 1; off < 8; off <<= 1) ssum += __shfl_xor(ssum, off, 8);
    float inv = 1.f / ssum;
#pragma unroll
    for (int m = 0; m < 4; ++m) Sl[c * 32 + l8 * 4 + m] = ex[m] * inv;
  }
  __syncthreads();

  for (int e2 = t; e2 < 6144; e2 += 256) {
    int kd = e2 / 192;
    int co = e2 - kd * 192;
    float s = 0.f;
#pragma unroll
    for (int c = 0; c < 32; ++c)
      s = fmaf(Pl[co * 33 + c], Sl[c * 32 + kd], s);
    W2t[((size_t)b * C_ + h * HD + kd) * C_ + co] = s;
  }
}

// ---------------------------------------------------------------------------
// K4: y[b][co][n2] = proj_b[co] + sum_j W2t[b][j][co] * V[b][j][n2],
// V[b][j][n2] = qkv[b][n2/24][(n2%24)*576 + 384 + j]. grid (216, 8), block 256.
// ---------------------------------------------------------------------------
__global__ __launch_bounds__(256) void proj_gemm(
    const ushort_t* __restrict__ qkv, const float* __restrict__ W2t,
    const float* __restrict__ pb, float* __restrict__ y) {
  __shared__ float Vs[192 * 65];
  int t = threadIdx.x;
  int nb = blockIdx.x, b = blockIdx.y;
  int n2_0 = nb * 64;
  const ushort_t* basep = qkv + (size_t)b * THREEC * N_;
#pragma unroll 4
  for (int i = 0; i < 48; ++i) {
    int idx = t + i * 256;
    int n2l = idx / 192;
    int jj = idx - n2l * 192;
    int n2 = n2_0 + n2l;
    int o = n2 / 24, r = n2 - o * 24;
    Vs[jj * 65 + n2l] = bf2f(basep[(size_t)o * N_ + r * THREEC + 384 + jj]);
  }
  __syncthreads();

  int n2l = t & 63;
  int cg = __builtin_amdgcn_readfirstlane(t >> 6);
  int co0 = cg * 48;
  const float* w2b = W2t + (size_t)b * C_ * C_ + co0;
  float acc[48];
#pragma unroll
  for (int i = 0; i < 48; ++i) acc[i] = 0.f;

  for (int k = 0; k < 192; ++k) {
    float v = Vs[k * 65 + n2l];
    const float* wk = w2b + (size_t)k * C_;
#pragma unroll
    for (int i = 0; i < 48; ++i) acc[i] = fmaf(wk[i], v, acc[i]);
  }

  float* yb = y + ((size_t)b * C_ + co0) * N_ + n2_0 + n2l;
#pragma unroll
  for (int i = 0; i < 48; ++i)
    yb[(size_t)i * N_] = acc[i] + pb[co0 + i];
}

// ---------------------------------------------------------------------------
extern "C" void kernel_launch(void* const* d_in, const int* in_sizes, int n_in,
                              void* d_out, int out_size, void* d_ws, size_t ws_size,
                              hipStream_t stream) {
  const float* x      = (const float*)d_in[0];
  const float* qkv_w  = (const float*)d_in[1];
  const float* qkv_b  = (const float*)d_in[2];
  const float* temp   = (const float*)d_in[3];
  const float* proj_w = (const float*)d_in[4];
  const float* proj_b = (const float*)d_in[5];
  float* y = (float*)d_out;

  // ws: qkv bf16 127.4MB | xT bf16 42.5MB | Spart 1.67MB | W2t 1.18MB | wbf 0.22MB
  char* wp = (char*)d_ws;
  ushort_t* qkv = (ushort_t*)wp;            wp += (size_t)B_ * THREEC * N_ * 2;
  ushort_t* xT  = (ushort_t*)wp;            wp += (size_t)B_ * N_ * C_ * 2;
  float* Spart  = (float*)wp;               wp += (size_t)B_ * HEADS * 8 * 1088 * 4;
  float* W2t    = (float*)wp;               wp += (size_t)B_ * C_ * C_ * 4;
  ushort_t* wbf = (ushort_t*)wp;

  wconv<<<54, 256, 0, stream>>>(qkv_w, wbf);
  xt_conv<<<dim3(216, B_), 256, 0, stream>>>(x, xT);
  qkv_gemm_mfma<<<dim3(9, 108, B_), 256, 0, stream>>>(wbf, xT, qkv_b, qkv);
  attn_partial<<<dim3(8, HEADS, B_), 256, 0, stream>>>(qkv, Spart);
  attn_final<<<dim3(HEADS, B_), 256, 0, stream>>>(Spart, temp, proj_w, W2t);
  proj_gemm<<<dim3(216, B_), 256, 0, stream>>>(qkv, W2t, proj_b, y);
}

// Round 3
// 339.670 us; speedup vs baseline: 1.8024x; 1.3431x over previous
//
#include <hip/hip_runtime.h>

#define B_ 8
#define C_ 192
#define N_ 13824     // 24^3
#define HEADS 6
#define HD 32
#define THREEC 576

typedef unsigned short ushort_t;
typedef unsigned int uint_t;
typedef __attribute__((ext_vector_type(8))) short short8;
typedef __attribute__((ext_vector_type(4))) float f32x4;

__device__ __forceinline__ float bf2f(ushort_t u) {
  union { uint_t u; float f; } c; c.u = ((uint_t)u) << 16; return c.f;
}
__device__ __forceinline__ ushort_t f2bf(float f) {
  union { float f; uint_t u; } c; c.f = f;
  uint_t u = c.u;
  uint_t r = (u + 0x7fffu + ((u >> 16) & 1u)) >> 16;  // RNE (finite values)
  return (ushort_t)r;
}

// LDS row stride for bf16 tiles: 200 shorts = 100 dwords. 100 % 32 = 4, so
// fragment ds_read_b128 (16 lanes stepping rows) spreads 8 lanes/bank-quad
// = balanced (192-short rows put all 16 lanes on ONE quad: ~16-way conflict).
#define LROW 200

// Lane->unit permutation for staging writes: unit u of row r goes to lane with
// ul = (u + r%8) % 24, so write bank-quad = ul%8 is uniform over the wave.
// (u = (ul - r%8) mod 24 is a bijection per row; data placement unchanged.)
__device__ __forceinline__ void rowperm(int f, int& row, int& u) {
  row = f / 24;
  int ul = f - row * 24;
  int uu = ul - (row & 7);
  u = uu + ((uu < 0) ? 24 : 0);
}

// ---------------------------------------------------------------------------
// K0a: qkv_w fp32 -> bf16. grid 54.
// ---------------------------------------------------------------------------
__global__ __launch_bounds__(256) void wconv(const float* __restrict__ w,
                                             ushort_t* __restrict__ wbf) {
  int idx = (blockIdx.x * 256 + threadIdx.x) * 8;  // 54*256*8 = 110592
  float4 v0 = *(const float4*)&w[idx];
  float4 v1 = *(const float4*)&w[idx + 4];
  union { ushort_t us[8]; uint4 v; } pk;
  pk.us[0] = f2bf(v0.x); pk.us[1] = f2bf(v0.y); pk.us[2] = f2bf(v0.z); pk.us[3] = f2bf(v0.w);
  pk.us[4] = f2bf(v1.x); pk.us[5] = f2bf(v1.y); pk.us[6] = f2bf(v1.z); pk.us[7] = f2bf(v1.w);
  *(uint4*)&wbf[idx] = pk.v;
}

// ---------------------------------------------------------------------------
// K0b: transpose+convert x[b][c][n] fp32 -> xT[b][n][c] bf16. grid (216, 8).
// ---------------------------------------------------------------------------
__global__ __launch_bounds__(256) void xt_conv(const float* __restrict__ x,
                                               ushort_t* __restrict__ xT) {
  __shared__ ushort_t tile[64 * 200];
  int t = threadIdx.x;
  int n0 = blockIdx.x * 64, b = blockIdx.y;
  const float* xb = x + (size_t)b * C_ * N_;
  int n4 = t & 15, cp = t >> 4;
#pragma unroll
  for (int it = 0; it < 6; ++it) {
    int c = (cp + it * 16) * 2;
    float4 v0 = *(const float4*)&xb[(size_t)c * N_ + n0 + n4 * 4];
    float4 v1 = *(const float4*)&xb[(size_t)(c + 1) * N_ + n0 + n4 * 4];
    float a0[4] = {v0.x, v0.y, v0.z, v0.w};
    float a1[4] = {v1.x, v1.y, v1.z, v1.w};
#pragma unroll
    for (int i = 0; i < 4; ++i) {
      uint_t wd = (uint_t)f2bf(a0[i]) | ((uint_t)f2bf(a1[i]) << 16);
      *(uint_t*)&tile[(n4 * 4 + i) * 200 + c] = wd;
    }
  }
  __syncthreads();
  ushort_t* xTb = xT + ((size_t)b * N_ + n0) * C_;
  int r = t >> 2, q = t & 3;
#pragma unroll
  for (int j = 0; j < 6; ++j) {
    int chunk = q * 6 + j;
    uint4 v = *(const uint4*)&tile[r * 200 + chunk * 8];
    *(uint4*)&xTb[r * 192 + chunk * 8] = v;
  }
}

// ---------------------------------------------------------------------------
// K1: MFMA bf16 GEMM: qkv[b][o][n] = sum_c wbf[o][c]*xT[b][n][c] + bias[o].
// BM=64 (o), BN=128 (n), K=192 one-shot in padded LDS. grid (9, 108, 8).
// 4 waves: 2x2, each 32(o) x 64(n) = 2x4 frags of 16x16x32.
// ---------------------------------------------------------------------------
__global__ __launch_bounds__(256) void qkv_gemm_mfma(
    const ushort_t* __restrict__ wbf, const ushort_t* __restrict__ xT,
    const float* __restrict__ bias, ushort_t* __restrict__ qkv) {
  __shared__ ushort_t As[64 * LROW];   // [o][c], row stride 400 B
  __shared__ ushort_t Bs[128 * LROW];  // [n][c]
  int t = threadIdx.x;
  int o0 = blockIdx.x * 64, n0 = blockIdx.y * 128, b = blockIdx.z;
  int w = t >> 6, lane = t & 63;
  int ln16 = lane & 15, q4 = lane >> 4;

  const ushort_t* Asrc = wbf + (size_t)o0 * C_;
  const ushort_t* Bsrc = xT + ((size_t)b * N_ + n0) * C_;

  // ---- stage: coalesced-ish loads to VGPR, permuted balanced LDS writes ----
  uint4 breg2[12]; int brow[12], bu[12];
#pragma unroll
  for (int j = 0; j < 12; ++j) {
    int f = (w * 12 + j) * 64 + lane;       // 16B units, 0..3071
    rowperm(f, brow[j], bu[j]);
    breg2[j] = *(const uint4*)(Bsrc + brow[j] * C_ + bu[j] * 8);
  }
  uint4 areg[6]; int arow[6], au[6];
#pragma unroll
  for (int j = 0; j < 6; ++j) {
    int f = (w * 6 + j) * 64 + lane;        // 0..1535
    rowperm(f, arow[j], au[j]);
    areg[j] = *(const uint4*)(Asrc + arow[j] * C_ + au[j] * 8);
  }
#pragma unroll
  for (int j = 0; j < 12; ++j)
    *(uint4*)&Bs[brow[j] * LROW + bu[j] * 8] = breg2[j];
#pragma unroll
  for (int j = 0; j < 6; ++j)
    *(uint4*)&As[arow[j] * LROW + au[j] * 8] = areg[j];

  float breg[2][4];
#pragma unroll
  for (int mi = 0; mi < 2; ++mi)
#pragma unroll
    for (int r = 0; r < 4; ++r)
      breg[mi][r] = bias[o0 + (w >> 1) * 32 + mi * 16 + q4 * 4 + r];

  f32x4 acc[2][4];
#pragma unroll
  for (int mi = 0; mi < 2; ++mi)
#pragma unroll
    for (int ni = 0; ni < 4; ++ni) acc[mi][ni] = (f32x4){0.f, 0.f, 0.f, 0.f};

  __syncthreads();

  int mrow = (w >> 1) * 32, ncol = (w & 1) * 64;
#pragma unroll
  for (int kk = 0; kk < 6; ++kk) {
    int k0 = kk * 32 + q4 * 8;
    short8 a[2], bb[4];
#pragma unroll
    for (int mi = 0; mi < 2; ++mi)
      a[mi] = *(const short8*)&As[(mrow + mi * 16 + ln16) * LROW + k0];
#pragma unroll
    for (int ni = 0; ni < 4; ++ni)
      bb[ni] = *(const short8*)&Bs[(ncol + ni * 16 + ln16) * LROW + k0];
#pragma unroll
    for (int mi = 0; mi < 2; ++mi)
#pragma unroll
      for (int ni = 0; ni < 4; ++ni)
        acc[mi][ni] = __builtin_amdgcn_mfma_f32_16x16x32_bf16(
            a[mi], bb[ni], acc[mi][ni], 0, 0, 0);
  }

  // ---- epilogue: +bias, bf16, pack n-pairs via shfl, b32 stores ----
#pragma unroll
  for (int mi = 0; mi < 2; ++mi)
#pragma unroll
    for (int ni = 0; ni < 4; ++ni)
#pragma unroll
      for (int r = 0; r < 4; ++r) {
        float v = acc[mi][ni][r] + breg[mi][r];
        uint_t bf = f2bf(v);
        uint_t pv = (uint_t)__shfl_xor((int)bf, 1);
        if (!(lane & 1)) {
          int o_l = mrow + mi * 16 + q4 * 4 + r;
          int n_l = ncol + ni * 16 + ln16;
          *(uint_t*)&qkv[(size_t)(b * THREEC + o0 + o_l) * N_ + n0 + n_l] =
              bf | (pv << 16);
        }
      }
}

// ---------------------------------------------------------------------------
// K2: per (b,h,chunk): partial S[c][d], nq[c], nk[d]. grid (8, 6, 8), block 256.
// ---------------------------------------------------------------------------
__global__ __launch_bounds__(256) void attn_partial(
    const ushort_t* __restrict__ qkv, float* __restrict__ Spart) {
  __shared__ float sh[4608];
  int t = threadIdx.x;
  int chunk = blockIdx.x, h = blockIdx.y, b = blockIdx.z;
  int j = t & 31, g8 = t >> 5;
  int tg = t >> 6, tl = t & 63;
  int c0 = (tl & 7) * 4, d0 = (tl >> 3) * 4;
  float acc[4][4];
#pragma unroll
  for (int i = 0; i < 4; ++i)
#pragma unroll
    for (int m = 0; m < 4; ++m) acc[i][m] = 0.f;
  float sqq = 0.f, sqk = 0.f;
  const ushort_t* basep = qkv + (size_t)b * THREEC * N_;
  int n2base = chunk * 1728;

  for (int p = 0; p < 27; ++p) {
    __syncthreads();
#pragma unroll
    for (int i = 0; i < 8; ++i) {
      int n2l = g8 * 8 + i;
      int n2 = n2base + p * 64 + n2l;
      int o = n2 / 24, r = n2 - o * 24;
      const ushort_t* rp = basep + (size_t)o * N_ + r * THREEC + h * HD + j;
      float qv = bf2f(rp[0]);
      float kv = bf2f(rp[C_]);
      sh[n2l * 32 + j] = qv;
      sh[2048 + n2l * 32 + j] = kv;
      sqq = fmaf(qv, qv, sqq);
      sqk = fmaf(kv, kv, sqk);
    }
    __syncthreads();
#pragma unroll
    for (int i = 0; i < 16; ++i) {
      int n2l = tg * 16 + i;
      float4 q4 = *(const float4*)&sh[n2l * 32 + c0];
      float4 k4 = *(const float4*)&sh[2048 + n2l * 32 + d0];
      float q[4] = {q4.x, q4.y, q4.z, q4.w};
      float kk[4] = {k4.x, k4.y, k4.z, k4.w};
#pragma unroll
      for (int ii = 0; ii < 4; ++ii)
#pragma unroll
        for (int mm = 0; mm < 4; ++mm)
          acc[ii][mm] = fmaf(q[ii], kk[mm], acc[ii][mm]);
    }
  }
  __syncthreads();
#pragma unroll
  for (int ii = 0; ii < 4; ++ii)
#pragma unroll
    for (int mm = 0; mm < 4; ++mm)
      sh[tg * 1024 + (c0 + ii) * 32 + (d0 + mm)] = acc[ii][mm];
  sh[4096 + g8 * 32 + j] = sqq;
  sh[4352 + g8 * 32 + j] = sqk;
  __syncthreads();

  float* outp = Spart + (size_t)((b * HEADS + h) * 8 + chunk) * 1088;
  for (int e = t; e < 1024; e += 256)
    outp[e] = sh[e] + sh[1024 + e] + sh[2048 + e] + sh[3072 + e];
  if (t < 32) {
    float s = 0.f;
#pragma unroll
    for (int g = 0; g < 8; ++g) s += sh[4096 + g * 32 + t];
    outp[1024 + t] = s;
  } else if (t < 64) {
    int jj = t - 32;
    float s = 0.f;
#pragma unroll
    for (int g = 0; g < 8; ++g) s += sh[4352 + g * 32 + jj];
    outp[1056 + jj] = s;
  }
}

// ---------------------------------------------------------------------------
// K3: reduce partials, softmax over d, then
// W2bf[b][co][h*32+d] = bf16( sum_c proj_w[co][c*6+h]*attn[c][d] ).
// grid (6, 8) = (h, b), block 256.
// ---------------------------------------------------------------------------
__global__ __launch_bounds__(256) void attn_final(
    const float* __restrict__ Spart, const float* __restrict__ temp,
    const float* __restrict__ proj_w, ushort_t* __restrict__ W2bf) {
  __shared__ float Sl[1024];
  __shared__ float invq[32], invk[32];
  __shared__ float Pl[192 * 33];
  int t = threadIdx.x;
  int h = blockIdx.x, b = blockIdx.y;
  const float* base = Spart + (size_t)((b * HEADS + h) * 8) * 1088;

  for (int e = t; e < 1024; e += 256) {
    float s = 0.f;
#pragma unroll
    for (int ch = 0; ch < 8; ++ch) s += base[ch * 1088 + e];
    Sl[e] = s;
  }
  if (t < 64) {
    int jj = t & 31;
    int off = 1024 + (t >> 5) * 32 + jj;
    float s = 0.f;
#pragma unroll
    for (int ch = 0; ch < 8; ++ch) s += base[ch * 1088 + off];
    float inv = 1.f / fmaxf(sqrtf(s), 1e-12f);
    if (t < 32) invq[jj] = inv; else invk[jj] = inv;
  }
  for (int e = t; e < 6144; e += 256) {
    int co = e >> 5, c = e & 31;
    Pl[co * 33 + c] = proj_w[(size_t)co * C_ + c * HEADS + h];
  }
  __syncthreads();

  {
    int c = t >> 3, l8 = t & 7;
    float tmpv = temp[h];
    float iq = invq[c];
    float lg[4];
#pragma unroll
    for (int m = 0; m < 4; ++m) {
      int d = l8 * 4 + m;
      lg[m] = Sl[c * 32 + d] * iq * invk[d] * tmpv;
    }
    float mx = fmaxf(fmaxf(lg[0], lg[1]), fmaxf(lg[2], lg[3]));
    for (int off = 1; off < 8; off <<= 1) mx = fmaxf(mx, __shfl_xor(mx, off, 8));
    float ex[4]; float ssum = 0.f;
#pragma unroll
    for (int m = 0; m < 4; ++m) { ex[m] = __expf(lg[m] - mx); ssum += ex[m]; }
    for (int off = 1; off < 8; off <<= 1) ssum += __shfl_xor(ssum, off, 8);
    float inv = 1.f / ssum;
#pragma unroll
    for (int m = 0; m < 4; ++m) Sl[c * 32 + l8 * 4 + m] = ex[m] * inv;
  }
  __syncthreads();

  // W2 in A-operand layout: [co][j=h*32+d], bf16
  for (int e2 = t; e2 < 6144; e2 += 256) {
    int co = e2 >> 5, d = e2 & 31;
    float s = 0.f;
#pragma unroll
    for (int c = 0; c < 32; ++c)
      s = fmaf(Pl[co * 33 + c], Sl[c * 32 + d], s);
    W2bf[((size_t)b * C_ + co) * C_ + h * HD + d] = f2bf(s);
  }
}

// ---------------------------------------------------------------------------
// K4: MFMA GEMM y[b][co][n2] = proj_b[co] + sum_j W2[b][co][j] * V[b][n2][j].
// V rows are j-contiguous in qkv's scrambled layout (no transpose needed):
// V[b][n2][j] = qkv[b][ (n2/24)*N + (n2%24)*576 + 384 + j ].
// BM=64 (co), BN=128 (n2). grid (3, 108, 8), block 256.
// ---------------------------------------------------------------------------
__global__ __launch_bounds__(256) void proj_mfma(
    const ushort_t* __restrict__ qkv, const ushort_t* __restrict__ W2bf,
    const float* __restrict__ pb, float* __restrict__ y) {
  __shared__ ushort_t As[64 * LROW];   // [co][j]
  __shared__ ushort_t Bs[128 * LROW];  // [n2][j]
  int t = threadIdx.x;
  int o0 = blockIdx.x * 64, n2_0 = blockIdx.y * 128, b = blockIdx.z;
  int w = t >> 6, lane = t & 63;
  int ln16 = lane & 15, q4 = lane >> 4;

  const ushort_t* Asrc = W2bf + ((size_t)b * C_ + o0) * C_;
  const ushort_t* basep = qkv + (size_t)b * THREEC * N_;

  uint4 breg2[12]; int brow[12], bu[12];
#pragma unroll
  for (int j = 0; j < 12; ++j) {
    int f = (w * 12 + j) * 64 + lane;
    rowperm(f, brow[j], bu[j]);
    int n2 = n2_0 + brow[j];
    int o = n2 / 24, r2 = n2 - o * 24;
    breg2[j] = *(const uint4*)(basep + (size_t)o * N_ + r2 * THREEC + 384 + bu[j] * 8);
  }
  uint4 areg[6]; int arow[6], au[6];
#pragma unroll
  for (int j = 0; j < 6; ++j) {
    int f = (w * 6 + j) * 64 + lane;
    rowperm(f, arow[j], au[j]);
    areg[j] = *(const uint4*)(Asrc + arow[j] * C_ + au[j] * 8);
  }
#pragma unroll
  for (int j = 0; j < 12; ++j)
    *(uint4*)&Bs[brow[j] * LROW + bu[j] * 8] = breg2[j];
#pragma unroll
  for (int j = 0; j < 6; ++j)
    *(uint4*)&As[arow[j] * LROW + au[j] * 8] = areg[j];

  float breg[2][4];
#pragma unroll
  for (int mi = 0; mi < 2; ++mi)
#pragma unroll
    for (int r = 0; r < 4; ++r)
      breg[mi][r] = pb[o0 + (w >> 1) * 32 + mi * 16 + q4 * 4 + r];

  f32x4 acc[2][4];
#pragma unroll
  for (int mi = 0; mi < 2; ++mi)
#pragma unroll
    for (int ni = 0; ni < 4; ++ni) acc[mi][ni] = (f32x4){0.f, 0.f, 0.f, 0.f};

  __syncthreads();

  int mrow = (w >> 1) * 32, ncol = (w & 1) * 64;
#pragma unroll
  for (int kk = 0; kk < 6; ++kk) {
    int k0 = kk * 32 + q4 * 8;
    short8 a[2], bb[4];
#pragma unroll
    for (int mi = 0; mi < 2; ++mi)
      a[mi] = *(const short8*)&As[(mrow + mi * 16 + ln16) * LROW + k0];
#pragma unroll
    for (int ni = 0; ni < 4; ++ni)
      bb[ni] = *(const short8*)&Bs[(ncol + ni * 16 + ln16) * LROW + k0];
#pragma unroll
    for (int mi = 0; mi < 2; ++mi)
#pragma unroll
      for (int ni = 0; ni < 4; ++ni)
        acc[mi][ni] = __builtin_amdgcn_mfma_f32_16x16x32_bf16(
            a[mi], bb[ni], acc[mi][ni], 0, 0, 0);
  }

  // epilogue: fp32 y, 16-lane-contiguous 64B stores
#pragma unroll
  for (int mi = 0; mi < 2; ++mi)
#pragma unroll
    for (int ni = 0; ni < 4; ++ni)
#pragma unroll
      for (int r = 0; r < 4; ++r) {
        int co_l = mrow + mi * 16 + q4 * 4 + r;
        int n_l = ncol + ni * 16 + ln16;
        y[((size_t)b * C_ + o0 + co_l) * N_ + n2_0 + n_l] =
            acc[mi][ni][r] + breg[mi][r];
      }
}

// ---------------------------------------------------------------------------
extern "C" void kernel_launch(void* const* d_in, const int* in_sizes, int n_in,
                              void* d_out, int out_size, void* d_ws, size_t ws_size,
                              hipStream_t stream) {
  const float* x      = (const float*)d_in[0];
  const float* qkv_w  = (const float*)d_in[1];
  const float* qkv_b  = (const float*)d_in[2];
  const float* temp   = (const float*)d_in[3];
  const float* proj_w = (const float*)d_in[4];
  const float* proj_b = (const float*)d_in[5];
  float* y = (float*)d_out;

  // ws: qkv bf16 127.4MB | xT bf16 42.5MB | Spart 1.67MB | W2bf 0.59MB | wbf 0.22MB
  char* wp = (char*)d_ws;
  ushort_t* qkv  = (ushort_t*)wp;  wp += (size_t)B_ * THREEC * N_ * 2;
  ushort_t* xT   = (ushort_t*)wp;  wp += (size_t)B_ * N_ * C_ * 2;
  float* Spart   = (float*)wp;     wp += (size_t)B_ * HEADS * 8 * 1088 * 4;
  ushort_t* W2bf = (ushort_t*)wp;  wp += (size_t)B_ * C_ * C_ * 2;
  ushort_t* wbf  = (ushort_t*)wp;

  wconv<<<54, 256, 0, stream>>>(qkv_w, wbf);
  xt_conv<<<dim3(216, B_), 256, 0, stream>>>(x, xT);
  qkv_gemm_mfma<<<dim3(9, 108, B_), 256, 0, stream>>>(wbf, xT, qkv_b, qkv);
  attn_partial<<<dim3(8, HEADS, B_), 256, 0, stream>>>(qkv, Spart);
  attn_final<<<dim3(HEADS, B_), 256, 0, stream>>>(Spart, temp, proj_w, W2bf);
  proj_mfma<<<dim3(3, 108, B_), 256, 0, stream>>>(qkv, W2bf, proj_b, y);
}